// Round 5
// baseline (592.224 us; speedup 1.0000x reference)
//
#include <hip/hip_runtime.h>
#include <stdint.h>

typedef float floatx4 __attribute__((ext_vector_type(4)));
typedef __bf16 bf16x8 __attribute__((ext_vector_type(8)));
typedef unsigned int uintx4 __attribute__((ext_vector_type(4)));
typedef unsigned short ushort_t;

__device__ __forceinline__ float b2f(ushort_t u) {
  union { unsigned int i; float f; } x; x.i = ((unsigned int)u) << 16; return x.f;
}
__device__ __forceinline__ ushort_t f2b(float f) {
  union { float f; unsigned int i; } x; x.f = f;
  unsigned int i = x.i;
  return (ushort_t)((i + 0x7FFFu + ((i >> 16) & 1u)) >> 16);  // RNE
}
__device__ __forceinline__ uintx4 ld16(const void* p) {
  uintx4 v; __builtin_memcpy(&v, p, 16); return v;
}
__device__ __forceinline__ void st16(void* p, uintx4 v) { __builtin_memcpy(p, &v, 16); }
__device__ __forceinline__ floatx4 f4splat(float x) { floatx4 v = {x, x, x, x}; return v; }
__device__ __forceinline__ void sched_fence() { asm volatile("" ::: "memory"); }
__device__ __forceinline__ bool insane(float v) { return !(fabsf(v) < 1e10f); }

__device__ __forceinline__ floatx4 mfma16(uintx4 a, uintx4 b, floatx4 c) {
  return __builtin_amdgcn_mfma_f32_16x16x32_bf16(
      __builtin_bit_cast(bf16x8, a), __builtin_bit_cast(bf16x8, b), c, 0, 0, 0);
}

// ---------------------------------------------------------------------------
// GEMM: C[M,N] = A[M,K](bf16) @ Bt[N,K]^T(bf16) + bias(f32)
// EPI: 0 = bf16 out, 1 = f32 out, 2 = tanh-GELU -> bf16 out
// 128x128 tile, BK=32, 4 waves each 64x64, explicit LDS staging.
// ---------------------------------------------------------------------------
template <int EPI>
__global__ __launch_bounds__(256, 2) void gemm_bt(
    const ushort_t* __restrict__ A, const ushort_t* __restrict__ Bt,
    const float* __restrict__ bias, void* __restrict__ Cout,
    int N, int K, unsigned int* __restrict__ flag) {
  __shared__ alignas(16) ushort_t lA[128 * 32];
  __shared__ alignas(16) ushort_t lB[128 * 32];
  const int tid = threadIdx.x;
  const int wave = tid >> 6, lane = tid & 63;
  const int quad = lane >> 4, l16 = lane & 15;
  const int bm = blockIdx.y * 128, bn = blockIdx.x * 128;
  const int wm = (wave >> 1) * 64, wn = (wave & 1) * 64;

  const int r0 = tid >> 2;   // 0..63
  const int cc = tid & 3;    // 0..3
  const ushort_t* Ag = A + (size_t)(bm + r0) * K + cc * 8;
  const ushort_t* Bg = Bt + (size_t)(bn + r0) * K + cc * 8;
  const size_t rstep = (size_t)64 * K;

  floatx4 acc[4][4];
#pragma unroll
  for (int i = 0; i < 4; i++)
#pragma unroll
    for (int j = 0; j < 4; j++) acc[i][j] = f4splat(0.f);

  for (int k0 = 0; k0 < K; k0 += 32) {
    __syncthreads();
    uintx4 a0 = ld16(Ag + k0);
    uintx4 a1 = ld16(Ag + rstep + k0);
    uintx4 b0 = ld16(Bg + k0);
    uintx4 b1 = ld16(Bg + rstep + k0);
    st16(&lA[r0 * 32 + cc * 8], a0);
    st16(&lA[(r0 + 64) * 32 + cc * 8], a1);
    st16(&lB[r0 * 32 + cc * 8], b0);
    st16(&lB[(r0 + 64) * 32 + cc * 8], b1);
    __syncthreads();
    uintx4 af[4], bf[4];
#pragma unroll
    for (int i = 0; i < 4; i++) af[i] = ld16(&lA[(wm + i * 16 + l16) * 32 + quad * 8]);
#pragma unroll
    for (int i = 0; i < 4; i++) bf[i] = ld16(&lB[(wn + i * 16 + l16) * 32 + quad * 8]);
#pragma unroll
    for (int mi = 0; mi < 4; mi++)
#pragma unroll
      for (int ni = 0; ni < 4; ni++) acc[mi][ni] = mfma16(af[mi], bf[ni], acc[mi][ni]);
  }

  float bv[4];
#pragma unroll
  for (int ni = 0; ni < 4; ni++) bv[ni] = bias[bn + wn + ni * 16 + l16];

  int bad = 0;
#pragma unroll
  for (int mi = 0; mi < 4; mi++)
#pragma unroll
    for (int ni = 0; ni < 4; ni++)
#pragma unroll
      for (int r = 0; r < 4; r++) {
        int row = bm + wm + mi * 16 + quad * 4 + r;
        int col = bn + wn + ni * 16 + l16;
        float v = acc[mi][ni][r] + bv[ni];
        if (EPI == 2) {
          // tanh-GELU == x * sigmoid(1.5957691*(x + 0.044715 x^3))
          float w = v + 0.044715f * v * v * v;
          float e = __builtin_amdgcn_exp2f(-2.3022084f * w);
          v = v * __builtin_amdgcn_rcpf(1.f + e);
        }
        if (insane(v)) { bad = 1; v = 0.f; }
        if (EPI == 1)
          ((float*)Cout)[(size_t)row * N + col] = v;
        else
          ((ushort_t*)Cout)[(size_t)row * N + col] = f2b(v);
      }
  if (bad) *flag = 1u;
}

// ---------------------------------------------------------------------------
// Flash self-attention. qkv: [8192,1536] bf16 (q|k|v, 8 heads x 64).
// vt: [2][512][4096] bf16. out: [8192,512] bf16. grid (32,16), 256 thr.
// ---------------------------------------------------------------------------
__global__ __launch_bounds__(256, 2) void flash_self(
    const ushort_t* __restrict__ qkv, const ushort_t* __restrict__ vt,
    ushort_t* __restrict__ outp, unsigned int* __restrict__ flag) {
  __shared__ alignas(16) ushort_t lK[64 * 72];
  __shared__ alignas(16) ushort_t lV[64 * 72];
  __shared__ alignas(16) ushort_t lP[128 * 72];
  const int tid = threadIdx.x, wave = tid >> 6, lane = tid & 63;
  const int quad = lane >> 4, l16 = lane & 15;
  const int bh = blockIdx.y, b = bh >> 3, h = bh & 7;
  const int qt = blockIdx.x;

  const ushort_t* Qb = qkv + (size_t)b * 4096 * 1536 + h * 64;
  const ushort_t* Kb = Qb + 512;
  const ushort_t* Vtb = vt + (size_t)bh * 64 * 4096;

  const int qr0 = qt * 128 + wave * 32;
  uintx4 qf[2][2];
#pragma unroll
  for (int mi = 0; mi < 2; mi++)
#pragma unroll
    for (int kf = 0; kf < 2; kf++)
      qf[mi][kf] = ld16(Qb + (size_t)(qr0 + mi * 16 + l16) * 1536 + kf * 32 + quad * 8);

  floatx4 O[2][4];
#pragma unroll
  for (int mi = 0; mi < 2; mi++)
#pragma unroll
    for (int dn = 0; dn < 4; dn++) O[mi][dn] = f4splat(0.f);
  floatx4 mr[2] = {f4splat(-1e30f), f4splat(-1e30f)};
  floatx4 lr[2] = {f4splat(0.f), f4splat(0.f)};
  const float c = 0.18033688f;  // log2(e)/8

  for (int kt = 0; kt < 64; kt++) {
    __syncthreads();
#pragma unroll
    for (int i = 0; i < 2; i++) {
      int ch = i * 256 + tid;
      int r = ch >> 3, c8 = ch & 7;
      st16(&lK[r * 72 + c8 * 8], ld16(Kb + (size_t)(kt * 64 + r) * 1536 + c8 * 8));
      st16(&lV[r * 72 + c8 * 8], ld16(Vtb + (size_t)r * 4096 + kt * 64 + c8 * 8));
    }
    __syncthreads();

    floatx4 S[2][4];
#pragma unroll
    for (int ni = 0; ni < 4; ni++) {
      uintx4 k0 = ld16(&lK[(ni * 16 + l16) * 72 + quad * 8]);
      uintx4 k1 = ld16(&lK[(ni * 16 + l16) * 72 + 32 + quad * 8]);
#pragma unroll
      for (int mi = 0; mi < 2; mi++) {
        floatx4 z = f4splat(0.f);
        z = mfma16(qf[mi][0], k0, z);
        z = mfma16(qf[mi][1], k1, z);
        S[mi][ni] = z;
      }
    }

#pragma unroll
    for (int mi = 0; mi < 2; mi++) {
      floatx4 cm = S[mi][0];
#pragma unroll
      for (int ni = 1; ni < 4; ni++)
#pragma unroll
        for (int r = 0; r < 4; r++) cm[r] = fmaxf(cm[r], S[mi][ni][r]);
#pragma unroll
      for (int off = 1; off < 16; off <<= 1)
#pragma unroll
        for (int r = 0; r < 4; r++) cm[r] = fmaxf(cm[r], __shfl_xor(cm[r], off));
      floatx4 mn, alpha;
#pragma unroll
      for (int r = 0; r < 4; r++) {
        mn[r] = fmaxf(mr[mi][r], cm[r]);
        alpha[r] = __builtin_amdgcn_exp2f((mr[mi][r] - mn[r]) * c);
      }
      mr[mi] = mn;
      floatx4 rs = f4splat(0.f);
#pragma unroll
      for (int ni = 0; ni < 4; ni++)
#pragma unroll
        for (int r = 0; r < 4; r++) {
          float p = __builtin_amdgcn_exp2f(S[mi][ni][r] * c - mn[r] * c);
          S[mi][ni][r] = p;
          rs[r] += p;
        }
#pragma unroll
      for (int off = 1; off < 16; off <<= 1)
#pragma unroll
        for (int r = 0; r < 4; r++) rs[r] += __shfl_xor(rs[r], off);
#pragma unroll
      for (int r = 0; r < 4; r++) lr[mi][r] = lr[mi][r] * alpha[r] + rs[r];
#pragma unroll
      for (int dn = 0; dn < 4; dn++)
#pragma unroll
        for (int r = 0; r < 4; r++) O[mi][dn][r] *= alpha[r];
#pragma unroll
      for (int ni = 0; ni < 4; ni++)
#pragma unroll
        for (int r = 0; r < 4; r++)
          lP[(wave * 32 + mi * 16 + quad * 4 + r) * 72 + ni * 16 + l16] = f2b(S[mi][ni][r]);
    }
    sched_fence();  // keep lP ds_reads below the lP stores (same-wave rows only)

#pragma unroll
    for (int kf = 0; kf < 2; kf++) {
      uintx4 pa0 = ld16(&lP[(wave * 32 + 0 + l16) * 72 + kf * 32 + quad * 8]);
      uintx4 pa1 = ld16(&lP[(wave * 32 + 16 + l16) * 72 + kf * 32 + quad * 8]);
#pragma unroll
      for (int dn = 0; dn < 4; dn++) {
        uintx4 vb = ld16(&lV[(dn * 16 + l16) * 72 + kf * 32 + quad * 8]);
        O[0][dn] = mfma16(pa0, vb, O[0][dn]);
        O[1][dn] = mfma16(pa1, vb, O[1][dn]);
      }
    }
  }

  int bad = 0;
#pragma unroll
  for (int mi = 0; mi < 2; mi++) {
    floatx4 inv;
#pragma unroll
    for (int r = 0; r < 4; r++) inv[r] = 1.0f / lr[mi][r];
#pragma unroll
    for (int dn = 0; dn < 4; dn++)
#pragma unroll
      for (int r = 0; r < 4; r++) {
        int row = b * 4096 + qt * 128 + wave * 32 + mi * 16 + quad * 4 + r;
        int col = h * 64 + dn * 16 + l16;
        float o = O[mi][dn][r] * inv[r];
        if (insane(o)) { bad = 1; o = 0.f; }
        outp[(size_t)row * 512 + col] = f2b(o);
      }
  }
  if (bad) *flag = 1u;
}

// ---------------------------------------------------------------------------
// Cross-attention: 77 keys (single tile padded to 96, one-pass softmax).
// qc,kc,vc bf16; out bf16.
// ---------------------------------------------------------------------------
__global__ __launch_bounds__(256, 2) void cross_attn(
    const ushort_t* __restrict__ qc, const ushort_t* __restrict__ kc,
    const ushort_t* __restrict__ vc, ushort_t* __restrict__ outp,
    unsigned int* __restrict__ flag) {
  __shared__ alignas(16) ushort_t lK[96 * 72];
  __shared__ alignas(16) ushort_t lV[64 * 104];
  __shared__ alignas(16) ushort_t lP[128 * 104];
  const int tid = threadIdx.x, wave = tid >> 6, lane = tid & 63;
  const int quad = lane >> 4, l16 = lane & 15;
  const int bh = blockIdx.y, b = bh >> 3, h = bh & 7;
  const int qt = blockIdx.x;

#pragma unroll
  for (int i = 0; i < 3; i++) {
    int ch = i * 256 + tid;  // 0..767
    int r = ch >> 3, c8 = ch & 7;
    uintx4 d = {0u, 0u, 0u, 0u};
    if (r < 77) d = ld16(kc + (size_t)(b * 77 + r) * 512 + h * 64 + c8 * 8);
    st16(&lK[r * 72 + c8 * 8], d);
  }
  for (int i = 0; i < 24; i++) {
    int e = i * 256 + tid;  // < 6144
    int dd = e / 96, s = e - dd * 96;
    ushort_t v = 0;
    if (s < 77) v = vc[(size_t)(b * 77 + s) * 512 + h * 64 + dd];
    lV[dd * 104 + s] = v;
  }
  __syncthreads();

  const int qr0 = qt * 128 + wave * 32;
  uintx4 qf[2][2];
#pragma unroll
  for (int mi = 0; mi < 2; mi++)
#pragma unroll
    for (int kf = 0; kf < 2; kf++)
      qf[mi][kf] =
          ld16(qc + (size_t)(b * 4096 + qr0 + mi * 16 + l16) * 512 + h * 64 + kf * 32 + quad * 8);

  floatx4 S[2][6];
#pragma unroll
  for (int ni = 0; ni < 6; ni++) {
    uintx4 k0 = ld16(&lK[(ni * 16 + l16) * 72 + quad * 8]);
    uintx4 k1 = ld16(&lK[(ni * 16 + l16) * 72 + 32 + quad * 8]);
#pragma unroll
    for (int mi = 0; mi < 2; mi++) {
      floatx4 z = f4splat(0.f);
      z = mfma16(qf[mi][0], k0, z);
      z = mfma16(qf[mi][1], k1, z);
      S[mi][ni] = z;
    }
  }
  const float c = 0.18033688f;
#pragma unroll
  for (int ni = 4; ni < 6; ni++)
    if (ni * 16 + l16 >= 77) {
      S[0][ni] = f4splat(-1e30f);
      S[1][ni] = f4splat(-1e30f);
    }

  floatx4 linv[2];
#pragma unroll
  for (int mi = 0; mi < 2; mi++) {
    floatx4 cm = S[mi][0];
#pragma unroll
    for (int ni = 1; ni < 6; ni++)
#pragma unroll
      for (int r = 0; r < 4; r++) cm[r] = fmaxf(cm[r], S[mi][ni][r]);
#pragma unroll
    for (int off = 1; off < 16; off <<= 1)
#pragma unroll
      for (int r = 0; r < 4; r++) cm[r] = fmaxf(cm[r], __shfl_xor(cm[r], off));
    floatx4 rs = f4splat(0.f);
#pragma unroll
    for (int ni = 0; ni < 6; ni++)
#pragma unroll
      for (int r = 0; r < 4; r++) {
        float p = __builtin_amdgcn_exp2f(S[mi][ni][r] * c - cm[r] * c);
        S[mi][ni][r] = p;
        rs[r] += p;
      }
#pragma unroll
    for (int off = 1; off < 16; off <<= 1)
#pragma unroll
      for (int r = 0; r < 4; r++) rs[r] += __shfl_xor(rs[r], off);
#pragma unroll
    for (int r = 0; r < 4; r++) linv[mi][r] = 1.0f / rs[r];
#pragma unroll
    for (int ni = 0; ni < 6; ni++)
#pragma unroll
      for (int r = 0; r < 4; r++)
        lP[(wave * 32 + mi * 16 + quad * 4 + r) * 104 + ni * 16 + l16] = f2b(S[mi][ni][r]);
  }
  sched_fence();

  floatx4 O[2][4];
#pragma unroll
  for (int mi = 0; mi < 2; mi++)
#pragma unroll
    for (int dn = 0; dn < 4; dn++) O[mi][dn] = f4splat(0.f);
#pragma unroll
  for (int kf = 0; kf < 3; kf++) {
    uintx4 pa0 = ld16(&lP[(wave * 32 + 0 + l16) * 104 + kf * 32 + quad * 8]);
    uintx4 pa1 = ld16(&lP[(wave * 32 + 16 + l16) * 104 + kf * 32 + quad * 8]);
#pragma unroll
    for (int dn = 0; dn < 4; dn++) {
      uintx4 vb = ld16(&lV[(dn * 16 + l16) * 104 + kf * 32 + quad * 8]);
      O[0][dn] = mfma16(pa0, vb, O[0][dn]);
      O[1][dn] = mfma16(pa1, vb, O[1][dn]);
    }
  }
  int bad = 0;
#pragma unroll
  for (int mi = 0; mi < 2; mi++)
#pragma unroll
    for (int dn = 0; dn < 4; dn++)
#pragma unroll
      for (int r = 0; r < 4; r++) {
        int row = b * 4096 + qt * 128 + wave * 32 + mi * 16 + quad * 4 + r;
        int col = h * 64 + dn * 16 + l16;
        float o = O[mi][dn][r] * linv[mi][r];
        if (insane(o)) { bad = 1; o = 0.f; }
        outp[(size_t)row * 512 + col] = f2b(o);
      }
  if (bad) *flag = 1u;
}

// ---------------------------------------------------------------------------
// Add + LayerNorm over D=512. p: f32. res: f32 (RESF=1) or bf16 (RESF=0).
// Outputs: out32 (f32, nullable) and outbf (bf16, nullable). One wave/row.
// ---------------------------------------------------------------------------
template <int RESF>
__global__ __launch_bounds__(256) void ln_kernel(
    const float* __restrict__ p, const void* __restrict__ resv,
    const float* __restrict__ g, const float* __restrict__ bb,
    float* __restrict__ out32, ushort_t* __restrict__ outbf,
    unsigned int* __restrict__ flag) {
  const int row = blockIdx.x * 4 + (threadIdx.x >> 6);
  const int lane = threadIdx.x & 63;
  const size_t base = (size_t)row * 512;
  float v[8];
  float s = 0.f, ss = 0.f;
#pragma unroll
  for (int i = 0; i < 4; i++) {
    int cidx = i * 128 + lane * 2;
    float2 pv; __builtin_memcpy(&pv, p + base + cidx, 8);
    float rx, ry;
    if (RESF) {
      float2 rv; __builtin_memcpy(&rv, (const float*)resv + base + cidx, 8);
      rx = rv.x; ry = rv.y;
    } else {
      unsigned int rr; __builtin_memcpy(&rr, (const ushort_t*)resv + base + cidx, 4);
      rx = b2f((ushort_t)(rr & 0xFFFFu));
      ry = b2f((ushort_t)(rr >> 16));
    }
    float a = pv.x + rx, b2 = pv.y + ry;
    v[2 * i] = a; v[2 * i + 1] = b2;
    s += a + b2;
    ss += a * a + b2 * b2;
  }
#pragma unroll
  for (int off = 1; off < 64; off <<= 1) {
    s += __shfl_xor(s, off);
    ss += __shfl_xor(ss, off);
  }
  float mean = s * (1.f / 512.f);
  float var = ss * (1.f / 512.f) - mean * mean;
  float rstd = rsqrtf(var + 1e-5f);
  int bad = 0;
#pragma unroll
  for (int i = 0; i < 4; i++) {
    int cidx = i * 128 + lane * 2;
    float2 gv; __builtin_memcpy(&gv, g + cidx, 8);
    float2 bv; __builtin_memcpy(&bv, bb + cidx, 8);
    float y0 = (v[2 * i] - mean) * rstd * gv.x + bv.x;
    float y1 = (v[2 * i + 1] - mean) * rstd * gv.y + bv.y;
    if (insane(y0)) { bad = 1; y0 = 0.f; }
    if (insane(y1)) { bad = 1; y1 = 0.f; }
    if (out32) {
      float2 o; o.x = y0; o.y = y1;
      __builtin_memcpy(out32 + base + cidx, &o, 8);
    }
    if (outbf) {
      unsigned int o16 = (unsigned int)f2b(y0) | ((unsigned int)f2b(y1) << 16);
      __builtin_memcpy(outbf + base + cidx, &o16, 4);
    }
  }
  if (bad) *flag = 1u;
}

// ---------------------------------------------------------------------------
// Small GEMMs for cross K/V: f32 [154,768] @ f32 [768,512] + bias -> bf16.
// ---------------------------------------------------------------------------
__global__ __launch_bounds__(256) void small_gemm2(
    const float* __restrict__ y, const float* __restrict__ wk,
    const float* __restrict__ bk, const float* __restrict__ wv,
    const float* __restrict__ bv, ushort_t* __restrict__ kout,
    ushort_t* __restrict__ vout, unsigned int* __restrict__ flag) {
  int bid = blockIdx.x;
  const float* W; const float* B; ushort_t* O;
  if (bid >= 308) { W = wv; B = bv; O = vout; bid -= 308; }
  else            { W = wk; B = bk; O = kout; }
  int idx = bid * 256 + threadIdx.x;
  if (idx >= 154 * 512) return;
  int r = idx >> 9, col = idx & 511;
  const float* ya = y + (size_t)r * 768;
  float acc = B[col];
#pragma unroll 4
  for (int k = 0; k < 768; k++) acc += ya[k] * W[(size_t)k * 512 + col];
  if (insane(acc)) { *flag = 1u; acc = 0.f; }
  O[idx] = f2b(acc);
}

// ---------------------------------------------------------------------------
// Transpose + convert f32 -> bf16 (weights), 32x32 LDS tiles
// ---------------------------------------------------------------------------
struct TransJob { const float* in; ushort_t* out; int ldi, ldo, nbx, start; };
struct TransJobs6 { TransJob j[6]; };

__global__ __launch_bounds__(256) void transpose6(TransJobs6 jobs) {
  __shared__ float t[32][33];
  int bid = blockIdx.x;
  int ji = 0;
#pragma unroll
  for (int i = 1; i < 6; i++)
    if (bid >= jobs.j[i].start) ji = i;
  TransJob J = jobs.j[ji];
  int local = bid - J.start;
  int by = local / J.nbx, bx = local - by * J.nbx;
  int r0 = by * 32, c0 = bx * 32;
  int tx = threadIdx.x & 31, ty = threadIdx.x >> 5;
#pragma unroll
  for (int i = 0; i < 4; i++)
    t[ty + 8 * i][tx] = J.in[(size_t)(r0 + ty + 8 * i) * J.ldi + c0 + tx];
  __syncthreads();
#pragma unroll
  for (int i = 0; i < 4; i++)
    J.out[(size_t)(c0 + ty + 8 * i) * J.ldo + r0 + tx] = f2b(t[tx][ty + 8 * i]);
}

// x f32 -> bf16, n elements (n % 1024 == 0), grid-stride not needed
__global__ __launch_bounds__(256) void xcvt(const float* __restrict__ in,
                                            ushort_t* __restrict__ out) {
  int i = (blockIdx.x * 256 + threadIdx.x) * 4;
  float4 v; __builtin_memcpy(&v, in + i, 16);
  ushort_t o[4] = {f2b(v.x), f2b(v.y), f2b(v.z), f2b(v.w)};
  __builtin_memcpy(out + i, o, 8);
}

// V slice of qkv bf16 [4096,512 @ ld 1536] -> vt[b][512][4096]; grid (16,128,2)
__global__ __launch_bounds__(256) void transpose_v(const ushort_t* __restrict__ qkv,
                                                   ushort_t* __restrict__ vt) {
  __shared__ ushort_t t[32][33];
  int b = blockIdx.z;
  const ushort_t* in = qkv + (size_t)b * 4096 * 1536 + 1024;
  ushort_t* out = vt + (size_t)b * 512 * 4096;
  int r0 = blockIdx.y * 32, c0 = blockIdx.x * 32;
  int tx = threadIdx.x & 31, ty = threadIdx.x >> 5;
#pragma unroll
  for (int i = 0; i < 4; i++)
    t[ty + 8 * i][tx] = in[(size_t)(r0 + ty + 8 * i) * 1536 + c0 + tx];
  __syncthreads();
#pragma unroll
  for (int i = 0; i < 4; i++)
    out[(size_t)(c0 + ty + 8 * i) * 4096 + r0 + tx] = t[tx][ty + 8 * i];
}

// ---------------------------------------------------------------------------
// Diagnostics
// ---------------------------------------------------------------------------
__global__ void init_flags(unsigned int* f) {
  if (threadIdx.x < 16) f[threadIdx.x] = 0u;
}
__global__ void verdict(const unsigned int* __restrict__ f, float* __restrict__ out) {
  if (threadIdx.x == 0) {
    int s = 0;
    for (int i = 12; i >= 1; i--)
      if (f[i]) s = i;
    if (s) out[0] = 1024.f + 64.f * (float)s;
  }
}
__global__ void ws_report(float* __restrict__ out, float code) {
  if (threadIdx.x == 0) out[0] = code;
}

// ---------------------------------------------------------------------------
// Workspace (64 MiB):
//  [ 0,24) QKV bf16 -> P f32 [0,16) -> QC bf16 [0,8) -> P2 f32 [0,16) -> FF bf16 [0,32)
//  [24,32) ATT bf16 (self) -> ATT2 bf16 (cross) -> FF tail
//  [32,40) VT bf16 -> then [32,48) XB0 f32 -> P3 f32
//  [48,56) XBF bf16 -> XB0bf bf16 -> XB1bf bf16 (ff1 A + ln3 residual)
//  [56,63) WT bf16 ; [63,..) KC,VC bf16 + FLAGS
// ---------------------------------------------------------------------------
extern "C" void kernel_launch(void* const* d_in, const int* in_sizes, int n_in,
                              void* d_out, int out_size, void* d_ws, size_t ws_size,
                              hipStream_t stream) {
  const size_t MiB = 1048576;
  if (ws_size < 64 * MiB) {
    int tier = (int)(ws_size / (16 * MiB));
    if (tier > 3) tier = 3;
    ws_report<<<1, 64, 0, stream>>>((float*)d_out, 4096.0f * (float)(tier + 1));
    return;
  }

  const float* x        = (const float*)d_in[0];
  const float* y        = (const float*)d_in[1];
  const float* sa_in_w  = (const float*)d_in[2];
  const float* sa_in_b  = (const float*)d_in[3];
  const float* sa_out_w = (const float*)d_in[4];
  const float* sa_out_b = (const float*)d_in[5];
  const float* ca_q_w   = (const float*)d_in[6];
  const float* ca_q_b   = (const float*)d_in[7];
  const float* ca_k_w   = (const float*)d_in[8];
  const float* ca_k_b   = (const float*)d_in[9];
  const float* ca_v_w   = (const float*)d_in[10];
  const float* ca_v_b   = (const float*)d_in[11];
  const float* ca_out_w = (const float*)d_in[12];
  const float* ca_out_b = (const float*)d_in[13];
  const float* ff_w1    = (const float*)d_in[14];
  const float* ff_b1    = (const float*)d_in[15];
  const float* ff_w2    = (const float*)d_in[16];
  const float* ff_b2    = (const float*)d_in[17];
  const float* ln1_g    = (const float*)d_in[18];
  const float* ln1_b    = (const float*)d_in[19];
  const float* ln2_g    = (const float*)d_in[20];
  const float* ln2_b    = (const float*)d_in[21];
  const float* ln3_g    = (const float*)d_in[22];
  const float* ln3_b    = (const float*)d_in[23];

  char* w = (char*)d_ws;
  ushort_t* QKV  = (ushort_t*)(w + 0);          // [0,24) bf16
  float*    P    = (float*)(w + 0);             // [0,16) f32 (QKV dead)
  ushort_t* QC   = (ushort_t*)(w + 0);          // [0,8)  bf16 (P dead)
  float*    P2   = (float*)(w + 0);             // [0,16) f32 (QC dead)
  ushort_t* FF   = (ushort_t*)(w + 0);          // [0,32) bf16 (P2,ATT2 dead)
  ushort_t* ATT  = (ushort_t*)(w + 24 * MiB);   // [24,32) bf16
  ushort_t* VT   = (ushort_t*)(w + 32 * MiB);   // [32,40) bf16
  float*    XB0  = (float*)(w + 32 * MiB);      // [32,48) f32 (VT dead)
  float*    P3   = (float*)(w + 32 * MiB);      // [32,48) f32 (XB0 dead)
  ushort_t* XBF  = (ushort_t*)(w + 48 * MiB);   // [48,56) bf16
  ushort_t* XB0b = (ushort_t*)(w + 48 * MiB);   //   then XB0 bf16
  ushort_t* XB1b = (ushort_t*)(w + 48 * MiB);   //   then XB1 bf16
  ushort_t* WT   = (ushort_t*)(w + 56 * MiB);   // [56,63) bf16
  ushort_t* KC   = (ushort_t*)(w + 63 * MiB);
  ushort_t* VC   = KC + 154 * 512;
  unsigned int* FLAGS = (unsigned int*)(w + 63 * MiB + 524288);

  ushort_t* WT_sain  = WT;                  // [1536,512]
  ushort_t* WT_saout = WT_sain + 786432;    // [512,512]
  ushort_t* WT_caq   = WT_saout + 262144;   // [512,512]
  ushort_t* WT_caout = WT_caq + 262144;     // [512,512]
  ushort_t* WT_ff1   = WT_caout + 262144;   // [2048,512]
  ushort_t* WT_ff2   = WT_ff1 + 1048576;    // [512,2048]

  init_flags<<<1, 64, 0, stream>>>(FLAGS);

  TransJobs6 tj;
  tj.j[0] = TransJob{sa_in_w,  WT_sain,  1536, 512, 48, 0};     // 768 blocks
  tj.j[1] = TransJob{sa_out_w, WT_saout, 512,  512, 16, 768};   // 256
  tj.j[2] = TransJob{ca_q_w,   WT_caq,   512,  512, 16, 1024};  // 256
  tj.j[3] = TransJob{ca_out_w, WT_caout, 512,  512, 16, 1280};  // 256
  tj.j[4] = TransJob{ff_w1,    WT_ff1,   2048, 512, 64, 1536};  // 1024
  tj.j[5] = TransJob{ff_w2,    WT_ff2,   512, 2048, 16, 2560};  // 1024 -> 3584
  transpose6<<<3584, 256, 0, stream>>>(tj);
  xcvt<<<4096, 256, 0, stream>>>(x, XBF);  // 8192*512 f32 -> bf16

  // self-attention
  gemm_bt<0><<<dim3(12, 64), 256, 0, stream>>>(XBF, WT_sain, sa_in_b, QKV, 1536, 512, FLAGS + 1);
  transpose_v<<<dim3(16, 128, 2), 256, 0, stream>>>(QKV, VT);
  flash_self<<<dim3(32, 16), 256, 0, stream>>>(QKV, VT, ATT, FLAGS + 2);
  gemm_bt<1><<<dim3(4, 64), 256, 0, stream>>>(ATT, WT_saout, sa_out_b, P, 512, 512, FLAGS + 3);
  ln_kernel<1><<<2048, 256, 0, stream>>>(P, x, ln1_g, ln1_b, XB0, XB0b, FLAGS + 4);

  // cross attention
  gemm_bt<0><<<dim3(4, 64), 256, 0, stream>>>(XB0b, WT_caq, ca_q_b, QC, 512, 512, FLAGS + 5);
  small_gemm2<<<616, 256, 0, stream>>>(y, ca_k_w, ca_k_b, ca_v_w, ca_v_b, KC, VC, FLAGS + 6);
  cross_attn<<<dim3(32, 16), 256, 0, stream>>>(QC, KC, VC, ATT, FLAGS + 7);
  gemm_bt<1><<<dim3(4, 64), 256, 0, stream>>>(ATT, WT_caout, ca_out_b, P2, 512, 512, FLAGS + 8);
  ln_kernel<1><<<2048, 256, 0, stream>>>(P2, XB0, ln2_g, ln2_b, nullptr, XB1b, FLAGS + 9);

  // feed-forward
  gemm_bt<2><<<dim3(16, 64), 256, 0, stream>>>(XB1b, WT_ff1, ff_b1, FF, 2048, 512, FLAGS + 10);
  gemm_bt<1><<<dim3(4, 64), 256, 0, stream>>>(FF, WT_ff2, ff_b2, P3, 512, 2048, FLAGS + 11);
  ln_kernel<0><<<2048, 256, 0, stream>>>(P3, XB1b, ln3_g, ln3_b, (float*)d_out, nullptr, FLAGS + 12);

  verdict<<<1, 64, 0, stream>>>(FLAGS, (float*)d_out);
}